// Round 7
// baseline (146.856 us; speedup 1.0000x reference)
//
#include <hip/hip_runtime.h>
#include <math.h>

namespace {
constexpr int kB = 2;
constexpr int kT = 4096;
constexpr int kD = 512;
constexpr int kH = 64;
constexpr int kRows = kB * kT;
constexpr int kRB = 16;   // rows per qkv block
constexpr int TQ = 16;    // queries per attn block
constexpr int NCH = 5;    // K/V chunks of 64 covering [t0-256, t0+63]
constexpr int CHS = 64;   // chunk size
constexpr int KVPAD = 68; // LDS row pad (f32 words)
}

// ---------------------------------------------------------------------------
// Kernel A: Q/K/V projection — R2 structure (3 waves, full-D, 16 rows) plus
// explicit register double-buffering (software pipeline depth 1).
// R2/R6 lesson: at VGPR=52 the compiler buffers nothing and every iteration
// pays serial L2 latency (~1050 cy/iter for 128 cy of FMA). Prefetching
// next iteration's W (4 scalars) and X (16 float4, wave-uniform -> SMEM)
// while computing the current one hides that latency. launch_bounds(192,1)
// gives the allocator headroom (~160 VGPR, still 3 waves/SIMD max).
// ---------------------------------------------------------------------------
__global__ __launch_bounds__(192, 1) void qkv_proj(const float* __restrict__ X,
                                                   const float* __restrict__ Wq,
                                                   const float* __restrict__ Wk,
                                                   const float* __restrict__ Wv,
                                                   float* __restrict__ Qo,
                                                   float* __restrict__ Ko,
                                                   float* __restrict__ Vo) {
  const int tid = threadIdx.x;
  const int m = tid >> 6;   // 0=Q, 1=K, 2=V (one wave each)
  const int h = tid & 63;
  const int row0 = blockIdx.x * kRB;
  const float* __restrict__ W = (m == 0) ? Wq : (m == 1) ? Wk : Wv;
  const float* __restrict__ xb = X + (size_t)row0 * kD;

  float acc[kRB];
#pragma unroll
  for (int r = 0; r < kRB; ++r) acc[r] = 0.f;

  float4 xcur[kRB], xnxt[kRB];
  float wc[4], wn[4];

  // prologue: load d=0 operands
#pragma unroll
  for (int j = 0; j < 4; ++j) wc[j] = W[j * kH + h];
#pragma unroll
  for (int r = 0; r < kRB; ++r)
    xcur[r] = *reinterpret_cast<const float4*>(xb + (size_t)r * kD);

  for (int d = 0; d < kD; d += 4) {
    const int dn = d + 4;
    if (dn < kD) {
      // issue next iteration's loads before this iteration's compute
#pragma unroll
      for (int j = 0; j < 4; ++j) wn[j] = W[(dn + j) * kH + h];
#pragma unroll
      for (int r = 0; r < kRB; ++r)
        xnxt[r] = *reinterpret_cast<const float4*>(xb + (size_t)r * kD + dn);
    }
#pragma unroll
    for (int r = 0; r < kRB; ++r) {
      acc[r] = fmaf(xcur[r].x, wc[0], acc[r]);
      acc[r] = fmaf(xcur[r].y, wc[1], acc[r]);
      acc[r] = fmaf(xcur[r].z, wc[2], acc[r]);
      acc[r] = fmaf(xcur[r].w, wc[3], acc[r]);
    }
#pragma unroll
    for (int j = 0; j < 4; ++j) wc[j] = wn[j];
#pragma unroll
    for (int r = 0; r < kRB; ++r) xcur[r] = xnxt[r];
  }

  float* __restrict__ out = (m == 0) ? Qo : (m == 1) ? Ko : Vo;
#pragma unroll
  for (int r = 0; r < kRB; ++r) out[(size_t)(row0 + r) * kH + h] = acc[r];
}

// ---------------------------------------------------------------------------
// Kernel B: sliding-window attention, 16 queries per block, LDS-staged K/V.
// (unchanged — ~16 us)
// ---------------------------------------------------------------------------
__global__ __launch_bounds__(256) void swin_attn(const float* __restrict__ Q,
                                                 const float* __restrict__ K,
                                                 const float* __restrict__ V,
                                                 float* __restrict__ O) {
  __shared__ float Qs[TQ][KVPAD];
  __shared__ float Sm[TQ][NCH * CHS];
  __shared__ float KV[CHS][KVPAD];

  const int tid = threadIdx.x;
  const int row0 = blockIdx.x * TQ;
  const int t0 = row0 & (kT - 1);
  const int b = row0 >> 12;
  const float* __restrict__ Kb = K + (size_t)b * kT * kH;
  const float* __restrict__ Vb = V + (size_t)b * kT * kH;

  {
    const int r = tid >> 4;
    const int h4 = (tid & 15) * 4;
    *reinterpret_cast<float4*>(&Qs[r][h4]) =
        *reinterpret_cast<const float4*>(&Q[(size_t)(row0 + r) * kH + h4]);
  }

  const int w = tid >> 6;
  const int lane = tid & 63;
  const int i0 = 4 * w;
  const int tmin = t0 + i0;
  const int tmax = t0 + i0 + 3;

  // ---- Phase A: scores ----
  for (int c = 0; c < NCH; ++c) {
    const int p0 = t0 - 256 + c * CHS;
    __syncthreads();
    for (int f = tid; f < CHS * kH / 4; f += 256) {
      const int r = f >> 4;
      const int h4 = (f & 15) * 4;
      const int p = p0 + r;
      float4 v = make_float4(0.f, 0.f, 0.f, 0.f);
      if (p >= 0 && p < kT)
        v = *reinterpret_cast<const float4*>(&Kb[(size_t)p * kH + h4]);
      *reinterpret_cast<float4*>(&KV[r][h4]) = v;
    }
    __syncthreads();

    const int lo = max(0, max(0, tmin - 255) - p0);
    const int hi = min(CHS - 1, tmax - p0);
    if (lo <= hi && lane >= lo && lane <= hi) {
      float s0 = 0.f, s1 = 0.f, s2 = 0.f, s3 = 0.f;
#pragma unroll
      for (int h0 = 0; h0 < kH; h0 += 4) {
        const float4 kv4 = *reinterpret_cast<const float4*>(&KV[lane][h0]);
        const float4 q0 = *reinterpret_cast<const float4*>(&Qs[i0 + 0][h0]);
        const float4 q1 = *reinterpret_cast<const float4*>(&Qs[i0 + 1][h0]);
        const float4 q2 = *reinterpret_cast<const float4*>(&Qs[i0 + 2][h0]);
        const float4 q3 = *reinterpret_cast<const float4*>(&Qs[i0 + 3][h0]);
        s0 = fmaf(kv4.w, q0.w, fmaf(kv4.z, q0.z, fmaf(kv4.y, q0.y, fmaf(kv4.x, q0.x, s0))));
        s1 = fmaf(kv4.w, q1.w, fmaf(kv4.z, q1.z, fmaf(kv4.y, q1.y, fmaf(kv4.x, q1.x, s1))));
        s2 = fmaf(kv4.w, q2.w, fmaf(kv4.z, q2.z, fmaf(kv4.y, q2.y, fmaf(kv4.x, q2.x, s2))));
        s3 = fmaf(kv4.w, q3.w, fmaf(kv4.z, q3.z, fmaf(kv4.y, q3.y, fmaf(kv4.x, q3.x, s3))));
      }
      const int jg = c * CHS + lane;
      Sm[i0 + 0][jg] = s0 * 0.125f;
      Sm[i0 + 1][jg] = s1 * 0.125f;
      Sm[i0 + 2][jg] = s2 * 0.125f;
      Sm[i0 + 3][jg] = s3 * 0.125f;
    }
  }
  __syncthreads();

  // ---- softmax: 16 lanes per query ----
  {
    const int i = tid >> 4;
    const int l = tid & 15;
    const int t = t0 + i;
    float sv[20];
    float mx = -INFINITY;
#pragma unroll
    for (int k2 = 0; k2 < 20; ++k2) {
      const int jg = l + 16 * k2;
      const int p = t0 - 256 + jg;
      const int jref = p - t + 255;
      const bool valid = (p >= 0) && (jref >= 0) && (jref <= 255) && (jref <= t);
      sv[k2] = valid ? Sm[i][jg] : -INFINITY;
      mx = fmaxf(mx, sv[k2]);
    }
#pragma unroll
    for (int off = 1; off < 16; off <<= 1) mx = fmaxf(mx, __shfl_xor(mx, off));
    const int n0 = (t < 255) ? min(t + 1, 255 - t) : 0;
    if (n0 > 0) mx = fmaxf(mx, 0.f);

    float sum = 0.f;
    float ev[20];
#pragma unroll
    for (int k2 = 0; k2 < 20; ++k2) {
      ev[k2] = (sv[k2] > -INFINITY) ? __expf(sv[k2] - mx) : 0.f;
      sum += ev[k2];
    }
#pragma unroll
    for (int off = 1; off < 16; off <<= 1) sum += __shfl_xor(sum, off);
    sum += (float)n0 * __expf(-mx);
    const float inv = 1.f / sum;
#pragma unroll
    for (int k2 = 0; k2 < 20; ++k2) Sm[i][l + 16 * k2] = ev[k2] * inv;
  }

  // ---- Phase B: PV ----
  float a0 = 0.f, a1 = 0.f, a2 = 0.f, a3 = 0.f;
  const int h = lane;
  for (int c = 0; c < NCH; ++c) {
    const int p0 = t0 - 256 + c * CHS;
    __syncthreads();
    for (int f = tid; f < CHS * kH / 4; f += 256) {
      const int r = f >> 4;
      const int h4 = (f & 15) * 4;
      const int p = p0 + r;
      float4 v = make_float4(0.f, 0.f, 0.f, 0.f);
      if (p >= 0 && p < kT)
        v = *reinterpret_cast<const float4*>(&Vb[(size_t)p * kH + h4]);
      *reinterpret_cast<float4*>(&KV[r][h4]) = v;
    }
    __syncthreads();

    const int lo = max(0, max(0, tmin - 255) - p0);
    const int hi = min(CHS - 1, tmax - p0);
    for (int q = lo; q <= hi; ++q) {
      const int jg = c * CHS + q;
      const float pv0 = Sm[i0 + 0][jg];
      const float pv1 = Sm[i0 + 1][jg];
      const float pv2 = Sm[i0 + 2][jg];
      const float pv3 = Sm[i0 + 3][jg];
      const float vv = KV[q][h];
      a0 = fmaf(pv0, vv, a0);
      a1 = fmaf(pv1, vv, a1);
      a2 = fmaf(pv2, vv, a2);
      a3 = fmaf(pv3, vv, a3);
    }
  }

  O[(size_t)(row0 + i0 + 0) * kH + h] = a0;
  O[(size_t)(row0 + i0 + 1) * kH + h] = a1;
  O[(size_t)(row0 + i0 + 2) * kH + h] = a2;
  O[(size_t)(row0 + i0 + 3) * kH + h] = a3;
}

// ---------------------------------------------------------------------------
extern "C" void kernel_launch(void* const* d_in, const int* in_sizes, int n_in,
                              void* d_out, int out_size, void* d_ws, size_t ws_size,
                              hipStream_t stream) {
  const float* X  = (const float*)d_in[0];
  const float* Wq = (const float*)d_in[1];
  const float* Wk = (const float*)d_in[2];
  const float* Wv = (const float*)d_in[3];
  float* Qo = (float*)d_ws;                 // [B*T][H]
  float* Ko = Qo + (size_t)kRows * kH;      // [B*T][H]
  float* Vo = Ko + (size_t)kRows * kH;      // [B*T][H]
  float* O = (float*)d_out;

  qkv_proj<<<kRows / kRB, 192, 0, stream>>>(X, Wq, Wk, Wv, Qo, Ko, Vo);
  swin_attn<<<kRows / TQ, 256, 0, stream>>>(Qo, Ko, Vo, O);
}

// Round 8
// 60.418 us; speedup vs baseline: 2.4307x; 2.4307x over previous
//
#include <hip/hip_runtime.h>
#include <hip/hip_bf16.h>
#include <math.h>

typedef short s16x8 __attribute__((ext_vector_type(8)));
typedef float f32x4 __attribute__((ext_vector_type(4)));

namespace {
constexpr int kB = 2;
constexpr int kT = 4096;
constexpr int kD = 512;          // GEMM K
constexpr int kH = 64;           // per-matrix N
constexpr int kRows = kB * kT;   // GEMM M = 8192
constexpr int kKS = kD / 32;     // 16 k-steps of 32

// workspace byte offsets
constexpr size_t oQ  = 0;
constexpr size_t oK  = oQ + (size_t)kRows * kH * 4;
constexpr size_t oV  = oK + (size_t)kRows * kH * 4;
constexpr size_t oAH = oV + (size_t)kRows * kH * 4;          // X hi, frag-major bf16
constexpr size_t oAL = oAH + (size_t)kRows * kD * 2;         // X lo
constexpr size_t oBH = oAL + (size_t)kRows * kD * 2;         // W hi
constexpr size_t oBL = oBH + (size_t)3 * kD * kH * 2;        // W lo
// total ~23.5 MB

// attention params (unchanged)
constexpr int TQ = 16;
constexpr int NCH = 5;
constexpr int CHS = 64;
constexpr int KVPAD = 68;
}

__device__ __forceinline__ void split_bf16(float x, short& h, short& l) {
  __hip_bfloat16 hb = __float2bfloat16(x);            // RNE
  float hf = __bfloat162float(hb);
  __hip_bfloat16 lb = __float2bfloat16(x - hf);
  h = *reinterpret_cast<short*>(&hb);
  l = *reinterpret_cast<short*>(&lb);
}

// ---------------------------------------------------------------------------
// Kernel 0: split X and W into hi/lo bf16 in MFMA fragment-major layout.
// A layout: AH[((mt*16 + ks)*64 + lane)*8 + e] = bf16(X[mt*16+(lane&15)]
//                                                  [ks*32+(lane>>4)*8+e])
// B layout: BH[(((mat*4+nf)*16 + ks)*64 + lane)*8 + e] =
//                         bf16(W_mat[ks*32+(lane>>4)*8+e][nf*16+(lane&15)])
// So the GEMM can load each fragment as ONE coalesced dwordx4.
// ---------------------------------------------------------------------------
__global__ __launch_bounds__(256) void prep_split(
    const float* __restrict__ X,
    const float* __restrict__ Wq, const float* __restrict__ Wk,
    const float* __restrict__ Wv,
    s16x8* __restrict__ AH, s16x8* __restrict__ AL,
    s16x8* __restrict__ BH, s16x8* __restrict__ BL) {
  const int w = threadIdx.x >> 6;
  const int lane = threadIdx.x & 63;
  const int bi = blockIdx.x;
  if (bi < 2048) {
    // ---- X part: one wave per (mt, ks) ----
    const int gw = bi * 4 + w;          // 0..8191
    const int mt = gw >> 4;
    const int ks = gw & 15;
    const int row = mt * 16 + (lane & 15);
    const int kb = ks * 32 + (lane >> 4) * 8;
    const float* xp = X + (size_t)row * kD + kb;
    const float4 x0 = *reinterpret_cast<const float4*>(xp);
    const float4 x1 = *reinterpret_cast<const float4*>(xp + 4);
    const float xv[8] = {x0.x, x0.y, x0.z, x0.w, x1.x, x1.y, x1.z, x1.w};
    s16x8 vh, vl;
#pragma unroll
    for (int e = 0; e < 8; ++e) {
      short h, l;
      split_bf16(xv[e], h, l);
      vh[e] = h;
      vl[e] = l;
    }
    const size_t idx = (size_t)gw * 64 + lane;
    AH[idx] = vh;
    AL[idx] = vl;
  } else {
    // ---- W part: one wave per (mat, nf, ks) ----
    const int gw = (bi - 2048) * 4 + w;  // 0..191
    if (gw < 192) {
      const int ks = gw & 15;
      const int mn = gw >> 4;            // mat*4 + nf
      const int mat = mn >> 2;
      const int nf = mn & 3;
      const float* __restrict__ W = (mat == 0) ? Wq : (mat == 1) ? Wk : Wv;
      const int n = nf * 16 + (lane & 15);
      const int kb = ks * 32 + (lane >> 4) * 8;
      s16x8 vh, vl;
#pragma unroll
      for (int e = 0; e < 8; ++e) {
        short h, l;
        split_bf16(W[(size_t)(kb + e) * kH + n], h, l);
        vh[e] = h;
        vl[e] = l;
      }
      const size_t idx = (size_t)gw * 64 + lane;
      BH[idx] = vh;
      BL[idx] = vl;
    }
  }
}

// ---------------------------------------------------------------------------
// Kernel 1: QKV projection via MFMA (split-bf16, 3 products: hh + lh + hl).
// Wave = 16 rows x 32 cols. No LDS, no barriers; frags load directly from
// the fragment-major arrays as coalesced dwordx4. Grid 768 x 256thr
// = 12 waves/CU.
// ---------------------------------------------------------------------------
__global__ __launch_bounds__(256) void qkv_mfma(
    const s16x8* __restrict__ AH, const s16x8* __restrict__ AL,
    const s16x8* __restrict__ BH, const s16x8* __restrict__ BL,
    float* __restrict__ Qo, float* __restrict__ Ko, float* __restrict__ Vo) {
  const int w = threadIdx.x >> 6;
  const int lane = threadIdx.x & 63;
  const int bi = blockIdx.x;
  const int mtg = bi & 127;      // m-tile group (4 tiles)
  const int rem = bi >> 7;       // 0..5
  const int mat = rem >> 1;      // 0=Q,1=K,2=V
  const int nh = rem & 1;        // which 32-col half
  const int mt = mtg * 4 + w;

  const s16x8* pah = AH + (size_t)mt * 16 * 64 + lane;
  const s16x8* pal = AL + (size_t)mt * 16 * 64 + lane;
  const int nf0 = nh * 2;
  const s16x8* pbh0 = BH + (size_t)(mat * 4 + nf0) * 16 * 64 + lane;
  const s16x8* pbl0 = BL + (size_t)(mat * 4 + nf0) * 16 * 64 + lane;
  const s16x8* pbh1 = BH + (size_t)(mat * 4 + nf0 + 1) * 16 * 64 + lane;
  const s16x8* pbl1 = BL + (size_t)(mat * 4 + nf0 + 1) * 16 * 64 + lane;

  f32x4 acc0 = {0.f, 0.f, 0.f, 0.f};
  f32x4 acc1 = {0.f, 0.f, 0.f, 0.f};

#pragma unroll
  for (int ks = 0; ks < kKS; ++ks) {
    const s16x8 ah = pah[ks * 64];
    const s16x8 al = pal[ks * 64];
    const s16x8 bh0 = pbh0[ks * 64];
    const s16x8 bl0 = pbl0[ks * 64];
    const s16x8 bh1 = pbh1[ks * 64];
    const s16x8 bl1 = pbl1[ks * 64];
    acc0 = __builtin_amdgcn_mfma_f32_16x16x32_bf16(ah, bh0, acc0, 0, 0, 0);
    acc1 = __builtin_amdgcn_mfma_f32_16x16x32_bf16(ah, bh1, acc1, 0, 0, 0);
    acc0 = __builtin_amdgcn_mfma_f32_16x16x32_bf16(al, bh0, acc0, 0, 0, 0);
    acc1 = __builtin_amdgcn_mfma_f32_16x16x32_bf16(al, bh1, acc1, 0, 0, 0);
    acc0 = __builtin_amdgcn_mfma_f32_16x16x32_bf16(ah, bl0, acc0, 0, 0, 0);
    acc1 = __builtin_amdgcn_mfma_f32_16x16x32_bf16(ah, bl1, acc1, 0, 0, 0);
  }

  float* __restrict__ out = (mat == 0) ? Qo : (mat == 1) ? Ko : Vo;
  const int row0 = mt * 16 + (lane >> 4) * 4;  // + reg (m89-verified C/D map)
  const int col = nh * 32 + (lane & 15);
#pragma unroll
  for (int r = 0; r < 4; ++r) {
    out[(size_t)(row0 + r) * kH + col] = acc0[r];
    out[(size_t)(row0 + r) * kH + col + 16] = acc1[r];
  }
}

// ---------------------------------------------------------------------------
// Kernel 2: sliding-window attention (unchanged, ~16 us).
// ---------------------------------------------------------------------------
__global__ __launch_bounds__(256) void swin_attn(const float* __restrict__ Q,
                                                 const float* __restrict__ K,
                                                 const float* __restrict__ V,
                                                 float* __restrict__ O) {
  __shared__ float Qs[TQ][KVPAD];
  __shared__ float Sm[TQ][NCH * CHS];
  __shared__ float KV[CHS][KVPAD];

  const int tid = threadIdx.x;
  const int row0 = blockIdx.x * TQ;
  const int t0 = row0 & (kT - 1);
  const int b = row0 >> 12;
  const float* __restrict__ Kb = K + (size_t)b * kT * kH;
  const float* __restrict__ Vb = V + (size_t)b * kT * kH;

  {
    const int r = tid >> 4;
    const int h4 = (tid & 15) * 4;
    *reinterpret_cast<float4*>(&Qs[r][h4]) =
        *reinterpret_cast<const float4*>(&Q[(size_t)(row0 + r) * kH + h4]);
  }

  const int w = tid >> 6;
  const int lane = tid & 63;
  const int i0 = 4 * w;
  const int tmin = t0 + i0;
  const int tmax = t0 + i0 + 3;

  // ---- Phase A: scores ----
  for (int c = 0; c < NCH; ++c) {
    const int p0 = t0 - 256 + c * CHS;
    __syncthreads();
    for (int f = tid; f < CHS * kH / 4; f += 256) {
      const int r = f >> 4;
      const int h4 = (f & 15) * 4;
      const int p = p0 + r;
      float4 v = make_float4(0.f, 0.f, 0.f, 0.f);
      if (p >= 0 && p < kT)
        v = *reinterpret_cast<const float4*>(&Kb[(size_t)p * kH + h4]);
      *reinterpret_cast<float4*>(&KV[r][h4]) = v;
    }
    __syncthreads();

    const int lo = max(0, max(0, tmin - 255) - p0);
    const int hi = min(CHS - 1, tmax - p0);
    if (lo <= hi && lane >= lo && lane <= hi) {
      float s0 = 0.f, s1 = 0.f, s2 = 0.f, s3 = 0.f;
#pragma unroll
      for (int h0 = 0; h0 < kH; h0 += 4) {
        const float4 kv4 = *reinterpret_cast<const float4*>(&KV[lane][h0]);
        const float4 q0 = *reinterpret_cast<const float4*>(&Qs[i0 + 0][h0]);
        const float4 q1 = *reinterpret_cast<const float4*>(&Qs[i0 + 1][h0]);
        const float4 q2 = *reinterpret_cast<const float4*>(&Qs[i0 + 2][h0]);
        const float4 q3 = *reinterpret_cast<const float4*>(&Qs[i0 + 3][h0]);
        s0 = fmaf(kv4.w, q0.w, fmaf(kv4.z, q0.z, fmaf(kv4.y, q0.y, fmaf(kv4.x, q0.x, s0))));
        s1 = fmaf(kv4.w, q1.w, fmaf(kv4.z, q1.z, fmaf(kv4.y, q1.y, fmaf(kv4.x, q1.x, s1))));
        s2 = fmaf(kv4.w, q2.w, fmaf(kv4.z, q2.z, fmaf(kv4.y, q2.y, fmaf(kv4.x, q2.x, s2))));
        s3 = fmaf(kv4.w, q3.w, fmaf(kv4.z, q3.z, fmaf(kv4.y, q3.y, fmaf(kv4.x, q3.x, s3))));
      }
      const int jg = c * CHS + lane;
      Sm[i0 + 0][jg] = s0 * 0.125f;
      Sm[i0 + 1][jg] = s1 * 0.125f;
      Sm[i0 + 2][jg] = s2 * 0.125f;
      Sm[i0 + 3][jg] = s3 * 0.125f;
    }
  }
  __syncthreads();

  // ---- softmax: 16 lanes per query ----
  {
    const int i = tid >> 4;
    const int l = tid & 15;
    const int t = t0 + i;
    float sv[20];
    float mx = -INFINITY;
#pragma unroll
    for (int k2 = 0; k2 < 20; ++k2) {
      const int jg = l + 16 * k2;
      const int p = t0 - 256 + jg;
      const int jref = p - t + 255;
      const bool valid = (p >= 0) && (jref >= 0) && (jref <= 255) && (jref <= t);
      sv[k2] = valid ? Sm[i][jg] : -INFINITY;
      mx = fmaxf(mx, sv[k2]);
    }
#pragma unroll
    for (int off = 1; off < 16; off <<= 1) mx = fmaxf(mx, __shfl_xor(mx, off));
    const int n0 = (t < 255) ? min(t + 1, 255 - t) : 0;
    if (n0 > 0) mx = fmaxf(mx, 0.f);

    float sum = 0.f;
    float ev[20];
#pragma unroll
    for (int k2 = 0; k2 < 20; ++k2) {
      ev[k2] = (sv[k2] > -INFINITY) ? __expf(sv[k2] - mx) : 0.f;
      sum += ev[k2];
    }
#pragma unroll
    for (int off = 1; off < 16; off <<= 1) sum += __shfl_xor(sum, off);
    sum += (float)n0 * __expf(-mx);
    const float inv = 1.f / sum;
#pragma unroll
    for (int k2 = 0; k2 < 20; ++k2) Sm[i][l + 16 * k2] = ev[k2] * inv;
  }

  // ---- Phase B: PV ----
  float a0 = 0.f, a1 = 0.f, a2 = 0.f, a3 = 0.f;
  const int h = lane;
  for (int c = 0; c < NCH; ++c) {
    const int p0 = t0 - 256 + c * CHS;
    __syncthreads();
    for (int f = tid; f < CHS * kH / 4; f += 256) {
      const int r = f >> 4;
      const int h4 = (f & 15) * 4;
      const int p = p0 + r;
      float4 v = make_float4(0.f, 0.f, 0.f, 0.f);
      if (p >= 0 && p < kT)
        v = *reinterpret_cast<const float4*>(&Vb[(size_t)p * kH + h4]);
      *reinterpret_cast<float4*>(&KV[r][h4]) = v;
    }
    __syncthreads();

    const int lo = max(0, max(0, tmin - 255) - p0);
    const int hi = min(CHS - 1, tmax - p0);
    for (int q = lo; q <= hi; ++q) {
      const int jg = c * CHS + q;
      const float pv0 = Sm[i0 + 0][jg];
      const float pv1 = Sm[i0 + 1][jg];
      const float pv2 = Sm[i0 + 2][jg];
      const float pv3 = Sm[i0 + 3][jg];
      const float vv = KV[q][h];
      a0 = fmaf(pv0, vv, a0);
      a1 = fmaf(pv1, vv, a1);
      a2 = fmaf(pv2, vv, a2);
      a3 = fmaf(pv3, vv, a3);
    }
  }

  O[(size_t)(row0 + i0 + 0) * kH + h] = a0;
  O[(size_t)(row0 + i0 + 1) * kH + h] = a1;
  O[(size_t)(row0 + i0 + 2) * kH + h] = a2;
  O[(size_t)(row0 + i0 + 3) * kH + h] = a3;
}

// ---------------------------------------------------------------------------
extern "C" void kernel_launch(void* const* d_in, const int* in_sizes, int n_in,
                              void* d_out, int out_size, void* d_ws, size_t ws_size,
                              hipStream_t stream) {
  const float* X  = (const float*)d_in[0];
  const float* Wq = (const float*)d_in[1];
  const float* Wk = (const float*)d_in[2];
  const float* Wv = (const float*)d_in[3];
  char* ws = (char*)d_ws;
  float* Qo = (float*)(ws + oQ);
  float* Ko = (float*)(ws + oK);
  float* Vo = (float*)(ws + oV);
  s16x8* AH = (s16x8*)(ws + oAH);
  s16x8* AL = (s16x8*)(ws + oAL);
  s16x8* BH = (s16x8*)(ws + oBH);
  s16x8* BL = (s16x8*)(ws + oBL);
  float* O = (float*)d_out;

  prep_split<<<2096, 256, 0, stream>>>(X, Wq, Wk, Wv, AH, AL, BH, BL);
  qkv_mfma<<<768, 256, 0, stream>>>(AH, AL, BH, BL, Qo, Ko, Vo);
  swin_attn<<<kRows / TQ, 256, 0, stream>>>(Qo, Ko, Vo, O);
}

// Round 9
// 36.490 us; speedup vs baseline: 4.0246x; 1.6558x over previous
//
#include <hip/hip_runtime.h>
#include <hip/hip_bf16.h>
#include <math.h>

typedef short s16x8 __attribute__((ext_vector_type(8)));
typedef float f32x4 __attribute__((ext_vector_type(4)));

namespace {
constexpr int kB = 2;
constexpr int kT = 4096;
constexpr int kD = 512;          // GEMM K
constexpr int kH = 64;           // per-matrix N
constexpr int kRows = kB * kT;   // GEMM M = 8192
constexpr int kKS = kD / 32;     // 16 k-steps of 32

// workspace byte offsets
constexpr size_t oQ  = 0;
constexpr size_t oK  = oQ + (size_t)kRows * kH * 4;
constexpr size_t oV  = oK + (size_t)kRows * kH * 4;
constexpr size_t oAH = oV + (size_t)kRows * kH * 4;          // X hi, frag-major bf16
constexpr size_t oAL = oAH + (size_t)kRows * kD * 2;         // X lo
constexpr size_t oBH = oAL + (size_t)kRows * kD * 2;         // W hi
constexpr size_t oBL = oBH + (size_t)3 * kD * kH * 2;        // W lo
// total ~23.5 MB

constexpr int TQ = 16;           // queries per attn block
constexpr int SPAD = 324;        // Sm row pad (f32 words): 2-way banks, 16B-aligned
}

__device__ __forceinline__ void split_bf16(float x, short& h, short& l) {
  __hip_bfloat16 hb = __float2bfloat16(x);            // RNE
  float hf = __bfloat162float(hb);
  __hip_bfloat16 lb = __float2bfloat16(x - hf);
  h = *reinterpret_cast<short*>(&hb);
  l = *reinterpret_cast<short*>(&lb);
}

__device__ __forceinline__ short bf16_hi(float x) {
  __hip_bfloat16 hb = __float2bfloat16(x);
  return *reinterpret_cast<short*>(&hb);
}

// ---------------------------------------------------------------------------
// Kernel 0: split X and W into hi/lo bf16 in MFMA fragment-major layout.
// (unchanged from R8)
// ---------------------------------------------------------------------------
__global__ __launch_bounds__(256) void prep_split(
    const float* __restrict__ X,
    const float* __restrict__ Wq, const float* __restrict__ Wk,
    const float* __restrict__ Wv,
    s16x8* __restrict__ AH, s16x8* __restrict__ AL,
    s16x8* __restrict__ BH, s16x8* __restrict__ BL) {
  const int w = threadIdx.x >> 6;
  const int lane = threadIdx.x & 63;
  const int bi = blockIdx.x;
  if (bi < 2048) {
    const int gw = bi * 4 + w;          // 0..8191
    const int mt = gw >> 4;
    const int ks = gw & 15;
    const int row = mt * 16 + (lane & 15);
    const int kb = ks * 32 + (lane >> 4) * 8;
    const float* xp = X + (size_t)row * kD + kb;
    const float4 x0 = *reinterpret_cast<const float4*>(xp);
    const float4 x1 = *reinterpret_cast<const float4*>(xp + 4);
    const float xv[8] = {x0.x, x0.y, x0.z, x0.w, x1.x, x1.y, x1.z, x1.w};
    s16x8 vh, vl;
#pragma unroll
    for (int e = 0; e < 8; ++e) {
      short h, l;
      split_bf16(xv[e], h, l);
      vh[e] = h;
      vl[e] = l;
    }
    const size_t idx = (size_t)gw * 64 + lane;
    AH[idx] = vh;
    AL[idx] = vl;
  } else {
    const int gw = (bi - 2048) * 4 + w;  // 0..191
    if (gw < 192) {
      const int ks = gw & 15;
      const int mn = gw >> 4;
      const int mat = mn >> 2;
      const int nf = mn & 3;
      const float* __restrict__ W = (mat == 0) ? Wq : (mat == 1) ? Wk : Wv;
      const int n = nf * 16 + (lane & 15);
      const int kb = ks * 32 + (lane >> 4) * 8;
      s16x8 vh, vl;
#pragma unroll
      for (int e = 0; e < 8; ++e) {
        short h, l;
        split_bf16(W[(size_t)(kb + e) * kH + n], h, l);
        vh[e] = h;
        vl[e] = l;
      }
      const size_t idx = (size_t)gw * 64 + lane;
      BH[idx] = vh;
      BL[idx] = vl;
    }
  }
}

// ---------------------------------------------------------------------------
// Kernel 1: QKV projection via MFMA (split-bf16, 3 products). (unchanged)
// ---------------------------------------------------------------------------
__global__ __launch_bounds__(256) void qkv_mfma(
    const s16x8* __restrict__ AH, const s16x8* __restrict__ AL,
    const s16x8* __restrict__ BH, const s16x8* __restrict__ BL,
    float* __restrict__ Qo, float* __restrict__ Ko, float* __restrict__ Vo) {
  const int w = threadIdx.x >> 6;
  const int lane = threadIdx.x & 63;
  const int bi = blockIdx.x;
  const int mtg = bi & 127;
  const int rem = bi >> 7;
  const int mat = rem >> 1;
  const int nh = rem & 1;
  const int mt = mtg * 4 + w;

  const s16x8* pah = AH + (size_t)mt * 16 * 64 + lane;
  const s16x8* pal = AL + (size_t)mt * 16 * 64 + lane;
  const int nf0 = nh * 2;
  const s16x8* pbh0 = BH + (size_t)(mat * 4 + nf0) * 16 * 64 + lane;
  const s16x8* pbl0 = BL + (size_t)(mat * 4 + nf0) * 16 * 64 + lane;
  const s16x8* pbh1 = BH + (size_t)(mat * 4 + nf0 + 1) * 16 * 64 + lane;
  const s16x8* pbl1 = BL + (size_t)(mat * 4 + nf0 + 1) * 16 * 64 + lane;

  f32x4 acc0 = {0.f, 0.f, 0.f, 0.f};
  f32x4 acc1 = {0.f, 0.f, 0.f, 0.f};

#pragma unroll
  for (int ks = 0; ks < kKS; ++ks) {
    const s16x8 ah = pah[ks * 64];
    const s16x8 al = pal[ks * 64];
    const s16x8 bh0 = pbh0[ks * 64];
    const s16x8 bl0 = pbl0[ks * 64];
    const s16x8 bh1 = pbh1[ks * 64];
    const s16x8 bl1 = pbl1[ks * 64];
    acc0 = __builtin_amdgcn_mfma_f32_16x16x32_bf16(ah, bh0, acc0, 0, 0, 0);
    acc1 = __builtin_amdgcn_mfma_f32_16x16x32_bf16(ah, bh1, acc1, 0, 0, 0);
    acc0 = __builtin_amdgcn_mfma_f32_16x16x32_bf16(al, bh0, acc0, 0, 0, 0);
    acc1 = __builtin_amdgcn_mfma_f32_16x16x32_bf16(al, bh1, acc1, 0, 0, 0);
    acc0 = __builtin_amdgcn_mfma_f32_16x16x32_bf16(ah, bl0, acc0, 0, 0, 0);
    acc1 = __builtin_amdgcn_mfma_f32_16x16x32_bf16(ah, bl1, acc1, 0, 0, 0);
  }

  float* __restrict__ out = (mat == 0) ? Qo : (mat == 1) ? Ko : Vo;
  const int row0 = mt * 16 + (lane >> 4) * 4;
  const int col = nh * 32 + (lane & 15);
#pragma unroll
  for (int r = 0; r < 4; ++r) {
    out[(size_t)(row0 + r) * kH + col] = acc0[r];
    out[(size_t)(row0 + r) * kH + col + 16] = acc1[r];
  }
}

// ---------------------------------------------------------------------------
// Kernel 2: sliding-window attention via MFMA.
// Block = 4 waves, 16 queries. Key band jg in [0,320), p = t0-256+jg.
// QK^T: split-bf16 (3 products) — scores need <1e-3 error.
// PV:   hi-only bf16 P and V (~3-4e-3 error, fine under 1.8e-2).
// Zero-pad key semantics via analytic n0 term (proven R3-R8).
// ---------------------------------------------------------------------------
__global__ __launch_bounds__(256) void swin_attn(const float* __restrict__ Q,
                                                 const float* __restrict__ K,
                                                 const float* __restrict__ V,
                                                 float* __restrict__ O) {
  __shared__ float Sm[TQ][SPAD];

  const int tid = threadIdx.x;
  const int w = tid >> 6;
  const int lane = tid & 63;
  const int row0 = blockIdx.x * TQ;
  const int t0 = row0 & (kT - 1);
  const int b = row0 >> 12;
  const float* __restrict__ Kb = K + (size_t)b * kT * kH;
  const float* __restrict__ Vb = V + (size_t)b * kT * kH;

  const int l15 = lane & 15;
  const int kcol = (lane >> 4) * 8;   // k-offset within a 32-wide k-tile

  // ---- Q fragments (A-operand): m = lane&15, k = kt*32 + kcol + e ----
  s16x8 qh[2], ql[2];
  {
    const float* qp = Q + (size_t)(row0 + l15) * kH + kcol;
#pragma unroll
    for (int kt = 0; kt < 2; ++kt) {
      const float4 a = *reinterpret_cast<const float4*>(qp + kt * 32);
      const float4 c = *reinterpret_cast<const float4*>(qp + kt * 32 + 4);
      const float qv[8] = {a.x, a.y, a.z, a.w, c.x, c.y, c.z, c.w};
#pragma unroll
      for (int e = 0; e < 8; ++e) {
        short hh, ll;
        split_bf16(qv[e], hh, ll);
        qh[kt][e] = hh;
        ql[kt][e] = ll;
      }
    }
  }

  // ---- QK^T: wave w covers n-tiles w*5 .. w*5+4 (16 keys each) ----
  f32x4 acc[5];
#pragma unroll
  for (int i = 0; i < 5; ++i) acc[i] = (f32x4){0.f, 0.f, 0.f, 0.f};

#pragma unroll
  for (int nt5 = 0; nt5 < 5; ++nt5) {
    const int nt = w * 5 + nt5;
    const int p = t0 - 256 + nt * 16 + l15;
    const int pc = min(max(p, 0), kT - 1);   // clamped; invalid slots masked later
    const float* kp = Kb + (size_t)pc * kH + kcol;
#pragma unroll
    for (int kt = 0; kt < 2; ++kt) {
      const float4 a = *reinterpret_cast<const float4*>(kp + kt * 32);
      const float4 c = *reinterpret_cast<const float4*>(kp + kt * 32 + 4);
      const float kv[8] = {a.x, a.y, a.z, a.w, c.x, c.y, c.z, c.w};
      s16x8 khh, kll;
#pragma unroll
      for (int e = 0; e < 8; ++e) {
        short hh, ll;
        split_bf16(kv[e], hh, ll);
        khh[e] = hh;
        kll[e] = ll;
      }
      acc[nt5] = __builtin_amdgcn_mfma_f32_16x16x32_bf16(qh[kt], khh, acc[nt5], 0, 0, 0);
      acc[nt5] = __builtin_amdgcn_mfma_f32_16x16x32_bf16(ql[kt], khh, acc[nt5], 0, 0, 0);
      acc[nt5] = __builtin_amdgcn_mfma_f32_16x16x32_bf16(qh[kt], kll, acc[nt5], 0, 0, 0);
    }
  }

  // C map: query m = (lane>>4)*4 + r, key col = nt*16 + (lane&15)
#pragma unroll
  for (int nt5 = 0; nt5 < 5; ++nt5) {
    const int nt = w * 5 + nt5;
    const int col = nt * 16 + l15;
#pragma unroll
    for (int r = 0; r < 4; ++r) Sm[(lane >> 4) * 4 + r][col] = acc[nt5][r] * 0.125f;
  }
  __syncthreads();

  // ---- softmax: 16 lanes per query (proven semantics incl. zero-pad n0) ----
  {
    const int i = tid >> 4;
    const int l = tid & 15;
    const int t = t0 + i;
    float sv[20];
    float mx = -INFINITY;
#pragma unroll
    for (int k2 = 0; k2 < 20; ++k2) {
      const int jg = l + 16 * k2;
      const int p = t0 - 256 + jg;
      const int jref = p - t + 255;
      const bool valid = (p >= 0) && (jref >= 0) && (jref <= 255) && (jref <= t);
      sv[k2] = valid ? Sm[i][jg] : -INFINITY;
      mx = fmaxf(mx, sv[k2]);
    }
#pragma unroll
    for (int off = 1; off < 16; off <<= 1) mx = fmaxf(mx, __shfl_xor(mx, off));
    const int n0 = (t < 255) ? min(t + 1, 255 - t) : 0;
    if (n0 > 0) mx = fmaxf(mx, 0.f);

    float sum = 0.f;
    float ev[20];
#pragma unroll
    for (int k2 = 0; k2 < 20; ++k2) {
      ev[k2] = (sv[k2] > -INFINITY) ? __expf(sv[k2] - mx) : 0.f;
      sum += ev[k2];
    }
#pragma unroll
    for (int off = 1; off < 16; off <<= 1) sum += __shfl_xor(sum, off);
    sum += (float)n0 * __expf(-mx);
    const float inv = 1.f / sum;
#pragma unroll
    for (int k2 = 0; k2 < 20; ++k2) Sm[i][l + 16 * k2] = ev[k2] * inv;
  }
  __syncthreads();

  // ---- PV: wave w covers h-columns w*16 .. w*16+15; K dim = 320 keys ----
  f32x4 oacc = {0.f, 0.f, 0.f, 0.f};
  const int hcol = w * 16 + l15;
#pragma unroll
  for (int kt = 0; kt < 10; ++kt) {
    // A = P: m = lane&15, k = kt*32 + kcol + e  (LDS, 2-way banks = free)
    const float* pr = &Sm[l15][kt * 32 + kcol];
    const float4 p0 = *reinterpret_cast<const float4*>(pr);
    const float4 p1 = *reinterpret_cast<const float4*>(pr + 4);
    s16x8 pa;
    pa[0] = bf16_hi(p0.x); pa[1] = bf16_hi(p0.y);
    pa[2] = bf16_hi(p0.z); pa[3] = bf16_hi(p0.w);
    pa[4] = bf16_hi(p1.x); pa[5] = bf16_hi(p1.y);
    pa[6] = bf16_hi(p1.z); pa[7] = bf16_hi(p1.w);
    // B = V: n = hcol, k rows = keys (clamped; P=0 on invalid slots)
    s16x8 vbf;
#pragma unroll
    for (int e = 0; e < 8; ++e) {
      const int kg = kt * 32 + kcol + e;
      const int p = t0 - 256 + kg;
      const int pc = min(max(p, 0), kT - 1);
      vbf[e] = bf16_hi(Vb[(size_t)pc * kH + hcol]);
    }
    oacc = __builtin_amdgcn_mfma_f32_16x16x32_bf16(pa, vbf, oacc, 0, 0, 0);
  }

#pragma unroll
  for (int r = 0; r < 4; ++r)
    O[(size_t)(row0 + (lane >> 4) * 4 + r) * kH + hcol] = oacc[r];
}

// ---------------------------------------------------------------------------
extern "C" void kernel_launch(void* const* d_in, const int* in_sizes, int n_in,
                              void* d_out, int out_size, void* d_ws, size_t ws_size,
                              hipStream_t stream) {
  const float* X  = (const float*)d_in[0];
  const float* Wq = (const float*)d_in[1];
  const float* Wk = (const float*)d_in[2];
  const float* Wv = (const float*)d_in[3];
  char* ws = (char*)d_ws;
  float* Qo = (float*)(ws + oQ);
  float* Ko = (float*)(ws + oK);
  float* Vo = (float*)(ws + oV);
  s16x8* AH = (s16x8*)(ws + oAH);
  s16x8* AL = (s16x8*)(ws + oAL);
  s16x8* BH = (s16x8*)(ws + oBH);
  s16x8* BL = (s16x8*)(ws + oBL);
  float* O = (float*)d_out;

  prep_split<<<2096, 256, 0, stream>>>(X, Wq, Wk, Wv, AH, AL, BH, BL);
  qkv_mfma<<<768, 256, 0, stream>>>(AH, AL, BH, BL, Qo, Ko, Vo);
  swin_attn<<<kRows / TQ, 256, 0, stream>>>(Qo, Ko, Vo, O);
}